// Round 3
// baseline (132.744 us; speedup 1.0000x reference)
//
#include <hip/hip_runtime.h>
#include <hip/hip_bf16.h>
#include <stdint.h>

#define UNITS 1024
#define IDIM  512
#define BATCH 2048
#define KTOT  1536   // UNITS + IDIM
#define NGATE 4096   // 4*UNITS
#define BK    64
#define NITER (KTOT / BK)   // 24

typedef short bf16x8 __attribute__((ext_vector_type(8)));   // 8 bf16 = 4 VGPRs
typedef float f32x4  __attribute__((ext_vector_type(4)));

#define AS3(p) ((__attribute__((address_space(3))) void*)(p))
#define AS1(p) ((const __attribute__((address_space(1))) void*)(p))

union P8 { bf16x8 v; __hip_bfloat16 e[8]; };

// ---------------------------------------------------------------------------
// prep: blocks [0,1536) cast-concat A = bf16(concat[h,x]); blocks [1536,4608)
// transpose W fp32 [1536][4096] -> Wt bf16 [4096][1536] (k-contiguous rows).
// (~11 us, near its 56.7 MB traffic floor of ~9 us -- not the lever.)
// ---------------------------------------------------------------------------
#define NBLK_A 1536
#define NBLK_T 3072

__global__ __launch_bounds__(256) void prep(
    const float* __restrict__ x, const float* __restrict__ h,
    const float* __restrict__ W,
    __hip_bfloat16* __restrict__ A, __hip_bfloat16* __restrict__ Wt) {
  __shared__ float tile[32][65];
  const int tid = threadIdx.x;
  if (blockIdx.x < NBLK_A) {
    const int id = blockIdx.x * 256 + tid;
    const int r = id / (KTOT / 8);
    const int k = (id % (KTOT / 8)) * 8;
    const float* src = (k < UNITS) ? h + (size_t)r * UNITS + k
                                   : x + (size_t)r * IDIM + (k - UNITS);
    const float4 v0 = ((const float4*)src)[0];
    const float4 v1 = ((const float4*)src)[1];
    P8 o;
    o.e[0] = __float2bfloat16(v0.x); o.e[1] = __float2bfloat16(v0.y);
    o.e[2] = __float2bfloat16(v0.z); o.e[3] = __float2bfloat16(v0.w);
    o.e[4] = __float2bfloat16(v1.x); o.e[5] = __float2bfloat16(v1.y);
    o.e[6] = __float2bfloat16(v1.z); o.e[7] = __float2bfloat16(v1.w);
    *(bf16x8*)(A + (size_t)r * KTOT + k) = o.v;
  } else {
    const int b  = blockIdx.x - NBLK_A;   // 0..3071
    const int kb = b >> 7;                // 0..23
    const int nb = b & 127;               // 0..127
    const int k0 = kb * 64, n0 = nb * 32;
    const int n4 = (tid & 7) * 4;
    const int kk = tid >> 3;              // 0..31
#pragma unroll
    for (int rr = 0; rr < 64; rr += 32) {
      const float4 v = *(const float4*)(W + (size_t)(k0 + kk + rr) * NGATE + n0 + n4);
      tile[n4 + 0][kk + rr] = v.x; tile[n4 + 1][kk + rr] = v.y;
      tile[n4 + 2][kk + rr] = v.z; tile[n4 + 3][kk + rr] = v.w;
    }
    __syncthreads();
    const int n  = tid >> 3;
    const int k8 = (tid & 7) * 8;
    P8 o;
#pragma unroll
    for (int j = 0; j < 8; ++j) o.e[j] = __float2bfloat16(tile[n][k8 + j]);
    *(bf16x8*)(Wt + (size_t)(n0 + n) * KTOT + k0 + k8) = o.v;
  }
}

// ---------------------------------------------------------------------------
// GEMM + fused LSTM -- R3: LDS-traffic cut via 128x64 wave tile (acc[8][4]).
//
// R2 post-mortem: kernel was ds_read-throughput-bound, not occupancy- or
// schedule-bound. At 64x64 wave tiles (acc[*][4] with 64 rows), FLOP per
// LDS-read-byte = 32.8; whole-gemm LDS traffic/CU = 6.1 MB = ~22 us at the
// measured 85 B/cyc ds_read_b128 rate -- i.e. the whole gemm time. Fix:
// 128x64 wave tile -> 43.7 FLOP/B (8 a-reads + 4 b-reads feed 32 MFMAs).
//
// Config: 256 threads / 4 waves (2 wr x 2 wu); block tile 256 rows x
// 32 units (x4 gates = 128 vcols); grid 8 mb x 32 ub = 256 = 1 block/CU.
// LDS 96 KB: [A0 32K][A1 32K][B0 16K][B1 16K]. 1 wave/SIMD is intentional:
// one wave's 64 back-to-back MFMAs/iter saturates the SIMD matrix pipe
// (~19 cyc/MFMA/SIMD), and launch_bounds(256,1) frees VGPRs (acc 128 +
// frags + addr ~250; no spill below 450 per m08).
//
// PROVEN pieces kept verbatim: 8-slot XOR swizzle chunk(row,k8)=row*8+
// (k8^(row&7)) with source-side pre-swizzle (0 conflicts measured);
// single-__syncthreads dbuf loop (issue prefetch -> full compute -> drain:
// L2 latency hides under compute; R1 proved counted-vmcnt adds nothing
// at this tile class). c_tm1 prefetch issued after the last barrier,
// overlapping the final 64-MFMA burst. No setprio (m190: hurts lockstep).
// ---------------------------------------------------------------------------
__global__ __launch_bounds__(256, 1) void lstm_gemm(
    const __hip_bfloat16* __restrict__ A,
    const __hip_bfloat16* __restrict__ Wt,
    const float* __restrict__ c_tm1,
    float* __restrict__ out) {
  __shared__ __attribute__((aligned(128))) char lds[98304];  // A0 A1 B0 B1

  const int tid  = threadIdx.x;
  const int w    = tid >> 6;     // wave 0..3 (uniform)
  const int lane = tid & 63;
  const int quad = lane >> 4;
  const int m16  = lane & 15;
  const int wr   = w >> 1;       // row half (0,1): rows wr*128..wr*128+127
  const int wu   = w & 1;        // unit half (0,1)

  const int mb = blockIdx.x >> 5;   // 0..7
  const int ub = blockIdx.x & 31;   // 0..31  (XCD = ub % 8)
  const int m0 = mb * 256;
  const int u0 = ub * 32;

  // Staging: 3072 16B chunks per iter (A 2048 + B 1024) / 256 thr = 12 each.
  const __hip_bfloat16* ptr[12];
  int dst[12];   // buffer-relative LDS offset (A-rel for s<8, +65536 B-rel)
#pragma unroll
  for (int s = 0; s < 12; ++s) {
    const int q = s * 4 + w;               // wave-uniform 0..47
    if (s < 8) {   // A tile: q 0..31, chunks 0..2047
      const int ci  = q * 64 + lane;
      const int row = ci >> 3;             // 0..255
      const int k8  = (ci & 7) ^ (row & 7);
      ptr[s] = A + (size_t)(m0 + row) * KTOT + k8 * 8;
      dst[s] = q * 1024;                   // 0..32767 within A buffer
    } else {       // B tile: qb 0..15, chunks 0..1023
      const int qb  = q - 32;
      const int cb  = qb * 64 + lane;
      const int vr  = cb >> 3;             // virtual col 0..127
      const int k8  = (cb & 7) ^ (vr & 7);
      const int wrow = ((vr >> 5) << 10) + u0 + (vr & 31);
      ptr[s] = Wt + (size_t)wrow * KTOT + k8 * 8;
      dst[s] = 65536 + qb * 1024;          // within B buffer 0
    }
  }

  f32x4 acc[8][4];
#pragma unroll
  for (int i = 0; i < 8; ++i)
#pragma unroll
    for (int g = 0; g < 4; ++g) {
      f32x4 z = {0.f, 0.f, 0.f, 0.f};
      acc[i][g] = z;
    }

  auto issue = [&](int koffE, int nxt) {
#pragma unroll
    for (int s = 0; s < 12; ++s) {
      const int off = dst[s] + ((s < 8) ? nxt * 32768 : nxt * 16384);
      __builtin_amdgcn_global_load_lds(AS1(ptr[s] + koffE), AS3(lds + off), 16, 0, 0);
    }
  };

  auto compute = [&](int cur) {
    const char* abuf = lds + cur * 32768;
    const char* bbuf = lds + 65536 + cur * 16384;
#pragma unroll
    for (int t = 0; t < 2; ++t) {
      bf16x8 a[8], b[4];
#pragma unroll
      for (int g = 0; g < 4; ++g) {
        const int vr   = g * 32 + wu * 16 + m16;
        const int slot = (t * 4 + quad) ^ (vr & 7);
        b[g] = *(const bf16x8*)(bbuf + (vr * 8 + slot) * 16);
      }
#pragma unroll
      for (int i = 0; i < 8; ++i) {
        const int row  = wr * 128 + i * 16 + m16;
        const int slot = (t * 4 + quad) ^ (row & 7);
        a[i] = *(const bf16x8*)(abuf + (row * 8 + slot) * 16);
      }
#pragma unroll
      for (int g = 0; g < 4; ++g)
#pragma unroll
        for (int i = 0; i < 8; ++i)
          acc[i][g] = __builtin_amdgcn_mfma_f32_16x16x32_bf16(a[i], b[g], acc[i][g], 0, 0, 0);
    }
  };

  // prologue: stage iter 0 into buffer 0
  issue(0, 0);
  __syncthreads();

  for (int it = 0; it < NITER - 1; ++it) {
    issue((it + 1) * BK, (it + 1) & 1);   // prefetch next tile
    compute(it & 1);
    __syncthreads();   // drains prefetch writes + fences reads of cur
  }

  // c_tm1 prefetch: issued before the final 64-MFMA burst, overlaps it
  const int u = u0 + wu * 16 + m16;
  float cpre[8][4];
#pragma unroll
  for (int i = 0; i < 8; ++i)
#pragma unroll
    for (int reg = 0; reg < 4; ++reg) {
      const int r = m0 + wr * 128 + i * 16 + quad * 4 + reg;
      cpre[i][reg] = c_tm1[(size_t)r * UNITS + u];
    }

  compute((NITER - 1) & 1);   // last iter (buffer 1)

  // fused LSTM epilogue -- all 4 gates in-lane
#pragma unroll
  for (int i = 0; i < 8; ++i)
#pragma unroll
    for (int reg = 0; reg < 4; ++reg) {
      const int r = m0 + wr * 128 + i * 16 + quad * 4 + reg;
      const float z0 = acc[i][0][reg];   // gate i
      const float z1 = acc[i][1][reg];   // gate f
      const float z2 = acc[i][2][reg];   // c_tilde
      const float z3 = acc[i][3][reg];   // gate o
      const float ig = 1.f / (1.f + __expf(-z0));
      const float fg = 1.f / (1.f + __expf(-z1));
      const float ct = 1.f - 2.f / (__expf(2.f * z2) + 1.f);   // tanh, inf-safe
      const float og = 1.f / (1.f + __expf(-z3));
      const float cc = fg * cpre[i][reg] + ig * ct;
      const float hh = og * (1.f - 2.f / (__expf(2.f * cc) + 1.f));
      out[(size_t)r * UNITS + u] = hh;
      out[(size_t)BATCH * UNITS + (size_t)r * UNITS + u] = cc;
    }
}

// ---------------------------------------------------------------------------
// Fallback (only if d_ws too small): naive fp32, correct but slow.
// ---------------------------------------------------------------------------
__global__ __launch_bounds__(256) void lstm_naive(
    const float* __restrict__ x, const float* __restrict__ h,
    const float* __restrict__ c_tm1, const float* __restrict__ W,
    float* __restrict__ out) {
  int idx = blockIdx.x * 256 + threadIdx.x;
  int r = idx / UNITS;
  int u = idx % UNITS;
  float z[4] = {0.f, 0.f, 0.f, 0.f};
  for (int k = 0; k < KTOT; ++k) {
    float a = (k < UNITS) ? h[(size_t)r * UNITS + k] : x[(size_t)r * IDIM + k - UNITS];
#pragma unroll
    for (int g = 0; g < 4; ++g)
      z[g] += a * W[(size_t)k * NGATE + g * UNITS + u];
  }
  float ig = 1.f / (1.f + __expf(-z[0]));
  float fg = 1.f / (1.f + __expf(-z[1]));
  float ct = 1.f - 2.f / (__expf(2.f * z[2]) + 1.f);
  float og = 1.f / (1.f + __expf(-z[3]));
  float cc = fg * c_tm1[(size_t)r * UNITS + u] + ig * ct;
  float hh = og * (1.f - 2.f / (__expf(2.f * cc) + 1.f));
  out[(size_t)r * UNITS + u] = hh;
  out[(size_t)BATCH * UNITS + (size_t)r * UNITS + u] = cc;
}

extern "C" void kernel_launch(void* const* d_in, const int* in_sizes, int n_in,
                              void* d_out, int out_size, void* d_ws, size_t ws_size,
                              hipStream_t stream) {
  const float* x = (const float*)d_in[0];   // [2048][512]
  const float* h = (const float*)d_in[1];   // [2048][1024]
  const float* c = (const float*)d_in[2];   // [2048][1024]
  const float* W = (const float*)d_in[3];   // [1536][4096]
  float* out = (float*)d_out;               // h then c, 2 x [2048][1024]

  const size_t needA  = (size_t)BATCH * KTOT * sizeof(__hip_bfloat16);  // 6.29 MB
  const size_t needWt = (size_t)NGATE * KTOT * sizeof(__hip_bfloat16);  // 12.58 MB
  if (ws_size < needA + needWt) {
    hipLaunchKernelGGL(lstm_naive, dim3((BATCH * UNITS) / 256), dim3(256), 0, stream,
                       x, h, c, W, out);
    return;
  }

  __hip_bfloat16* A  = (__hip_bfloat16*)d_ws;
  __hip_bfloat16* Wt = (__hip_bfloat16*)((char*)d_ws + needA);

  hipLaunchKernelGGL(prep, dim3(NBLK_A + NBLK_T), dim3(256), 0, stream, x, h, W, A, Wt);
  hipLaunchKernelGGL(lstm_gemm, dim3(256), dim3(256), 0, stream, A, Wt, c, out);
}